// Round 7
// baseline (81.186 us; speedup 1.0000x reference)
//
#include <hip/hip_runtime.h>
#include <math.h>

#define NJ 7
#define DTF 0.01f
#define GRAVF 9.81f

// per-thread LDS slot map (idx-major: addr = slot*64 + lane -> bank = lane%32,
// 2 lanes/bank = conflict-free). 126 slots * 64 lanes * 4 B = 32256 B.
#define S_SN(i)    (i)            // sin q      (7)
#define S_CS(i)    (7 + (i))      // cos q      (7)
#define S_QD(i)    (14 + (i))     // qd         (7)
#define S_TAU(i)   (21 + (i))     // tau, reused for qdd in pass 3 (7)
#define S_VU(i,k)  (28 + 6*(i) + (k))  // v_i (pass1) -> U_i (pass2)  (42)
#define S_CC(i,k)  (70 + 6*(i) + (k))  // c_i                          (42)
#define S_DI(i)    (112 + (i))    // dinv       (7)
#define S_UU(i)    (119 + (i))    // u          (7)
#define NSLOT 126

__device__ __forceinline__ void cross3(const float* a, const float* b, float* o){
    o[0] = a[1]*b[2] - a[2]*b[1];
    o[1] = a[2]*b[0] - a[0]*b[2];
    o[2] = a[0]*b[1] - a[1]*b[0];
}
__device__ __forceinline__ void mv3(const float* E, const float* x, float* y){
    y[0] = E[0]*x[0] + E[1]*x[1] + E[2]*x[2];
    y[1] = E[3]*x[0] + E[4]*x[1] + E[5]*x[2];
    y[2] = E[6]*x[0] + E[7]*x[1] + E[8]*x[2];
}
__device__ __forceinline__ void mtv3(const float* E, const float* x, float* y){
    y[0] = E[0]*x[0] + E[3]*x[1] + E[6]*x[2];
    y[1] = E[1]*x[0] + E[4]*x[1] + E[7]*x[2];
    y[2] = E[2]*x[0] + E[5]*x[1] + E[8]*x[2];
}
// y = S x, S sym6 {00,01,02,11,12,22}
__device__ __forceinline__ void symv(const float* S, const float* x, float* y){
    y[0] = S[0]*x[0] + S[1]*x[1] + S[2]*x[2];
    y[1] = S[1]*x[0] + S[3]*x[1] + S[4]*x[2];
    y[2] = S[2]*x[0] + S[4]*x[1] + S[5]*x[2];
}
__device__ __forceinline__ void mm3(const float* A, const float* B, float* o){
#pragma unroll
    for (int r = 0; r < 3; r++)
#pragma unroll
        for (int c = 0; c < 3; c++)
            o[r*3+c] = A[r*3]*B[c] + A[r*3+1]*B[3+c] + A[r*3+2]*B[6+c];
}
// o = A^T B
__device__ __forceinline__ void mtm3(const float* A, const float* B, float* o){
#pragma unroll
    for (int r = 0; r < 3; r++)
#pragma unroll
        for (int c = 0; c < 3; c++)
            o[r*3+c] = A[r]*B[c] + A[3+r]*B[3+c] + A[6+r]*B[6+c];
}
// o = E^T X E (X full 3x3)
__device__ __forceinline__ void congr(const float* E, const float* X, float* o){
    float t[9];
    mtm3(E, X, t);
    mm3(t, E, o);
}
// O = M * skew(p)   (columns of skew(p): (0,p2,-p1), (-p2,0,p0), (p1,-p0,0))
__device__ __forceinline__ void skewR(const float* M, const float* p, float* O){
#pragma unroll
    for (int r = 0; r < 3; r++){
        O[r*3+0] = M[r*3+1]*p[2] - M[r*3+2]*p[1];
        O[r*3+1] = M[r*3+2]*p[0] - M[r*3+0]*p[2];
        O[r*3+2] = M[r*3+0]*p[1] - M[r*3+1]*p[0];
    }
}
// O = skew(p) * M   (col c of O = p x col c of M)
__device__ __forceinline__ void skewL(const float* p, const float* M, float* O){
#pragma unroll
    for (int c = 0; c < 3; c++){
        O[0*3+c] = p[1]*M[2*3+c] - p[2]*M[1*3+c];
        O[1*3+c] = p[2]*M[0*3+c] - p[0]*M[2*3+c];
        O[2*3+c] = p[0]*M[1*3+c] - p[1]*M[0*3+c];
    }
}
__device__ __forceinline__ void symexp(const float* S, float* F){
    F[0]=S[0]; F[1]=S[1]; F[2]=S[2];
    F[3]=S[1]; F[4]=S[3]; F[5]=S[4];
    F[6]=S[2]; F[7]=S[4]; F[8]=S[5];
}
// E = R(q)^T @ R_tree[i]
__device__ __forceinline__ void makeE(const float* a, const float* __restrict__ Rt,
                                      float s, float c, float* E){
    float omc = 1.0f - c;
    float RT[9];
    RT[0] = c + omc*a[0]*a[0];       RT[1] =  s*a[2] + omc*a[0]*a[1]; RT[2] = -s*a[1] + omc*a[0]*a[2];
    RT[3] = -s*a[2] + omc*a[1]*a[0]; RT[4] = c + omc*a[1]*a[1];       RT[5] =  s*a[0] + omc*a[1]*a[2];
    RT[6] =  s*a[1] + omc*a[2]*a[0]; RT[7] = -s*a[0] + omc*a[2]*a[1]; RT[8] = c + omc*a[2]*a[2];
    float Rl[9];
#pragma unroll
    for (int k = 0; k < 9; k++) Rl[k] = Rt[k];
    mm3(RT, Rl, E);
}
// body spatial inertia: Ibar sym6 (SA), h = m*c (3), mass m
__device__ __forceinline__ void bodyI(const float* __restrict__ g_I, int i,
                                      float* SA, float* h, float& m){
    const float* I6 = g_I + i*36;
    SA[0]=I6[0]; SA[1]=I6[1]; SA[2]=I6[2];
    SA[3]=I6[7]; SA[4]=I6[8]; SA[5]=I6[14];
    h[0]=I6[16]; h[1]=I6[5]; h[2]=I6[9];
    m = I6[21];
}

__constant__ float QL_c[NJ] = {-2.9671f,-1.8326f,-2.9671f,-3.1416f,-2.9671f,-0.0873f,-2.9671f};
__constant__ float QU_c[NJ] = { 2.9671f, 1.8326f, 2.9671f, 0.0f,    2.9671f, 3.8223f, 2.9671f};

// Articulated Body Algorithm: 1 thread = 1 element, NO role split, NO barriers,
// NO matrix factorization. Three rolled passes; per-joint state in a
// per-thread-private LDS slice (lane-linear layout -> conflict-free).
// IA (articulated inertia) kept as blocks [[A,B],[B^T,C]], A,C sym6, B full9.
// Conventions match the reference exactly: motion vec [w; v],
// Xup = [[E,0],[-E p^, E]], E = R(q)^T R_tree, S = [a; 0],
// gravity as base acceleration a0 = [0,0,0, 0,0,+9.81].
__global__ __launch_bounds__(64, 1)
void panda_step(const float* __restrict__ x, const float* __restrict__ u,
                const float* __restrict__ g_ax, const float* __restrict__ g_Rt,
                const float* __restrict__ g_pt, const float* __restrict__ g_I,
                float* __restrict__ out, int B)
{
    __shared__ float s_buf[NSLOT*64];   // 32256 B -> 4 blocks/CU (grid-exact)
    const int lane = threadIdx.x;       // block = 64 = 1 wave
    const int e    = blockIdx.x*64 + lane;
    if (e >= B) return;                 // no barriers anywhere -> safe
#define SL(idx) s_buf[(idx)*64 + lane]

    // ---------------- phase 0: load, clip, sincos, stage ----------------
    float q[NJ], qd[NJ];
    {
        float xl[14];
        const float2* x2 = (const float2*)(x + e*14);
#pragma unroll
        for (int i = 0; i < 7; i++){ float2 v = x2[i]; xl[2*i] = v.x; xl[2*i+1] = v.y; }
#pragma unroll
        for (int i = 0; i < NJ; i++){
            q[i]  = fminf(fmaxf(xl[i], QL_c[i]), QU_c[i]);
            qd[i] = xl[NJ + i];
            float s, c; __sincosf(q[i], &s, &c);
            SL(S_SN(i))  = s;
            SL(S_CS(i))  = c;
            SL(S_QD(i))  = qd[i];
            SL(S_TAU(i)) = u[e*NJ + i];
        }
    }

    // ---------------- pass 1: forward velocities ----------------
    {
        float w[3] = {0.f,0.f,0.f}, vl[3] = {0.f,0.f,0.f};
#pragma unroll 1
        for (int i = 0; i < NJ; ++i){
            float a[3] = { g_ax[3*i], g_ax[3*i+1], g_ax[3*i+2] };
            float p[3] = { g_pt[3*i], g_pt[3*i+1], g_pt[3*i+2] };
            float sn = SL(S_SN(i)), cs = SL(S_CS(i)), qdi = SL(S_QD(i));
            float E[9]; makeE(a, g_Rt + 9*i, sn, cs, E);
            float cwp[3]; cross3(w, p, cwp);                 // w x p
            float t[3] = { vl[0]+cwp[0], vl[1]+cwp[1], vl[2]+cwp[2] };
            float nw[3], nl[3];
            mv3(E, w, nw); mv3(E, t, nl);
            nw[0] += a[0]*qdi; nw[1] += a[1]*qdi; nw[2] += a[2]*qdi;
#pragma unroll
            for (int k = 0; k < 3; k++){
                SL(S_VU(i,k))   = nw[k];
                SL(S_VU(i,3+k)) = nl[k];
                w[k] = nw[k]; vl[k] = nl[k];
            }
        }
    }

    // ---------------- pass 2: backward articulated inertia ----------------
    {
        float A[6], Bm[9], C[6];             // IA blocks
        float px[6] = {0.f,0.f,0.f,0.f,0.f,0.f};  // child pA contribution
        {
            float SA[6], h[3], m; bodyI(g_I, NJ-1, SA, h, m);
#pragma unroll
            for (int k = 0; k < 6; k++) A[k] = SA[k];
            Bm[0]=0.f;    Bm[1]=-h[2]; Bm[2]= h[1];
            Bm[3]= h[2];  Bm[4]=0.f;   Bm[5]=-h[0];
            Bm[6]=-h[1];  Bm[7]= h[0]; Bm[8]=0.f;
            C[0]=m; C[1]=0.f; C[2]=0.f; C[3]=m; C[4]=0.f; C[5]=m;
        }
#pragma unroll 1
        for (int i = NJ-1; i >= 0; --i){
            float a[3] = { g_ax[3*i], g_ax[3*i+1], g_ax[3*i+2] };
            float w[3], vl[3];
#pragma unroll
            for (int k = 0; k < 3; k++){ w[k] = SL(S_VU(i,k)); vl[k] = SL(S_VU(i,3+k)); }
            float qdi = SL(S_QD(i)), taui = SL(S_TAU(i));
            // pA = crf(v) (I_body v) + px
            float SAi[6], hi[3], mi; bodyI(g_I, i, SAi, hi, mi);
            float Ivt[3], hxl[3]; symv(SAi, w, Ivt); cross3(hi, vl, hxl);
#pragma unroll
            for (int k = 0; k < 3; k++) Ivt[k] += hxl[k];
            float hxw[3]; cross3(hi, w, hxw);
            float Ivb[3] = { mi*vl[0]-hxw[0], mi*vl[1]-hxw[1], mi*vl[2]-hxw[2] };
            float c1[3], c2[3], c3[3];
            cross3(w, Ivt, c1); cross3(vl, Ivb, c2); cross3(w, Ivb, c3);
            float pAt[3] = { c1[0]+c2[0]+px[0], c1[1]+c2[1]+px[1], c1[2]+c2[2]+px[2] };
            float pAb[3] = { c3[0]+px[3], c3[1]+px[4], c3[2]+px[5] };
            // U = IA S, d, u
            float Ut[3], Ub[3];
            symv(A, a, Ut); mtv3(Bm, a, Ub);
            float d = a[0]*Ut[0] + a[1]*Ut[1] + a[2]*Ut[2];
            float dinv = __builtin_amdgcn_rcpf(d);
            float uu = taui - (a[0]*pAt[0] + a[1]*pAt[1] + a[2]*pAt[2]);
#pragma unroll
            for (int k = 0; k < 3; k++){ SL(S_VU(i,k)) = Ut[k]; SL(S_VU(i,3+k)) = Ub[k]; }
            SL(S_DI(i)) = dinv;
            SL(S_UU(i)) = uu;
            // c_i = [qd (w x a); qd (vl x a)]   (c_0 == 0 analytically; store anyway)
            float wxa[3], lxa[3]; cross3(w, a, wxa); cross3(vl, a, lxa);
            float ct[3] = { qdi*wxa[0], qdi*wxa[1], qdi*wxa[2] };
            float cb[3] = { qdi*lxa[0], qdi*lxa[1], qdi*lxa[2] };
#pragma unroll
            for (int k = 0; k < 3; k++){ SL(S_CC(i,k)) = ct[k]; SL(S_CC(i,3+k)) = cb[k]; }
            if (i > 0){
                float p[3] = { g_pt[3*i], g_pt[3*i+1], g_pt[3*i+2] };
                float sn = SL(S_SN(i)), cs = SL(S_CS(i));
                float E[9]; makeE(a, g_Rt + 9*i, sn, cs, E);
                // rank-1 deflation: Ia = IA - dinv U U^T
                float rA[6], rB[9], rC[6];
                rA[0]=A[0]-dinv*Ut[0]*Ut[0]; rA[1]=A[1]-dinv*Ut[0]*Ut[1]; rA[2]=A[2]-dinv*Ut[0]*Ut[2];
                rA[3]=A[3]-dinv*Ut[1]*Ut[1]; rA[4]=A[4]-dinv*Ut[1]*Ut[2]; rA[5]=A[5]-dinv*Ut[2]*Ut[2];
#pragma unroll
                for (int r = 0; r < 3; r++)
#pragma unroll
                    for (int c = 0; c < 3; c++)
                        rB[r*3+c] = Bm[r*3+c] - dinv*Ut[r]*Ub[c];
                rC[0]=C[0]-dinv*Ub[0]*Ub[0]; rC[1]=C[1]-dinv*Ub[0]*Ub[1]; rC[2]=C[2]-dinv*Ub[0]*Ub[2];
                rC[3]=C[3]-dinv*Ub[1]*Ub[1]; rC[4]=C[4]-dinv*Ub[1]*Ub[2]; rC[5]=C[5]-dinv*Ub[2]*Ub[2];
                // pa = pA + Ia c + U dinv u
                float du = dinv*uu;
                float t1[3], t2[3];
                symv(rA, ct, t1); mv3(rB, cb, t2);
                float pat[3] = { pAt[0]+t1[0]+t2[0]+du*Ut[0],
                                 pAt[1]+t1[1]+t2[1]+du*Ut[1],
                                 pAt[2]+t1[2]+t2[2]+du*Ut[2] };
                mtv3(rB, ct, t1); symv(rC, cb, t2);
                float pab[3] = { pAb[0]+t1[0]+t2[0]+du*Ub[0],
                                 pAb[1]+t1[1]+t2[1]+du*Ub[1],
                                 pAb[2]+t1[2]+t2[2]+du*Ub[2] };
                // congruences to parent frame
                float Ff[9], AeF[9], CeF[9], tB[9], Bf[9];
                symexp(rA, Ff); congr(E, Ff, AeF);
                symexp(rC, Ff); congr(E, Ff, CeF);
                mtm3(E, rB, tB); mm3(tB, E, Bf);
                float Bp[9], Qm[9], PQ[9], LC[9];
                skewR(Bf, p, Bp);
                skewR(CeF, p, Qm); skewL(p, Qm, PQ);
                skewL(p, CeF, LC);
                // new IA = body(i-1) + X^T Ia X
                float SAm[6], hm[3], mm_; bodyI(g_I, i-1, SAm, hm, mm_);
                A[0] = SAm[0] + AeF[0] - 2.0f*Bp[0]     - PQ[0];
                A[1] = SAm[1] + AeF[1] - (Bp[1]+Bp[3])  - PQ[1];
                A[2] = SAm[2] + AeF[2] - (Bp[2]+Bp[6])  - PQ[2];
                A[3] = SAm[3] + AeF[4] - 2.0f*Bp[4]     - PQ[4];
                A[4] = SAm[4] + AeF[5] - (Bp[5]+Bp[7])  - PQ[5];
                A[5] = SAm[5] + AeF[8] - 2.0f*Bp[8]     - PQ[8];
                Bm[0] = Bf[0]+LC[0];        Bm[1] = Bf[1]+LC[1]-hm[2]; Bm[2] = Bf[2]+LC[2]+hm[1];
                Bm[3] = Bf[3]+LC[3]+hm[2];  Bm[4] = Bf[4]+LC[4];       Bm[5] = Bf[5]+LC[5]-hm[0];
                Bm[6] = Bf[6]+LC[6]-hm[1];  Bm[7] = Bf[7]+LC[7]+hm[0]; Bm[8] = Bf[8]+LC[8];
                C[0] = mm_ + CeF[0]; C[1] = CeF[1]; C[2] = CeF[2];
                C[3] = mm_ + CeF[4]; C[4] = CeF[5]; C[5] = mm_ + CeF[8];
                // px_parent = X^T pa
                float tm[3], tf[3], cp[3];
                mtv3(E, pat, tm); mtv3(E, pab, tf);
                cross3(p, tf, cp);
                px[0]=tm[0]+cp[0]; px[1]=tm[1]+cp[1]; px[2]=tm[2]+cp[2];
                px[3]=tf[0];       px[4]=tf[1];       px[5]=tf[2];
            }
        }
    }

    // ---------------- pass 3: forward accelerations -> qdd ----------------
    {
        float at[3] = {0.f,0.f,0.f}, ab[3] = {0.f,0.f,GRAVF};
#pragma unroll 1
        for (int i = 0; i < NJ; ++i){
            float a[3] = { g_ax[3*i], g_ax[3*i+1], g_ax[3*i+2] };
            float p[3] = { g_pt[3*i], g_pt[3*i+1], g_pt[3*i+2] };
            float sn = SL(S_SN(i)), cs = SL(S_CS(i));
            float E[9]; makeE(a, g_Rt + 9*i, sn, cs, E);
            float axp[3]; cross3(at, p, axp);                 // at x p = -p^ at
            float t[3] = { ab[0]+axp[0], ab[1]+axp[1], ab[2]+axp[2] };
            float apt[3], apb[3];
            mv3(E, at, apt); mv3(E, t, apb);
#pragma unroll
            for (int k = 0; k < 3; k++){
                apt[k] += SL(S_CC(i,k));
                apb[k] += SL(S_CC(i,3+k));
            }
            float Ut[3] = { SL(S_VU(i,0)), SL(S_VU(i,1)), SL(S_VU(i,2)) };
            float Ub[3] = { SL(S_VU(i,3)), SL(S_VU(i,4)), SL(S_VU(i,5)) };
            float dinv = SL(S_DI(i)), uu = SL(S_UU(i));
            float qdd = dinv*(uu - (Ut[0]*apt[0]+Ut[1]*apt[1]+Ut[2]*apt[2]
                                   + Ub[0]*apb[0]+Ub[1]*apb[1]+Ub[2]*apb[2]));
            SL(S_TAU(i)) = qdd;                               // tau slot dead -> qdd
            at[0] = apt[0] + a[0]*qdd;
            at[1] = apt[1] + a[1]*qdd;
            at[2] = apt[2] + a[2]*qdd;
            ab[0] = apb[0]; ab[1] = apb[1]; ab[2] = apb[2];
        }
    }

    // ---------------- integrate + store ----------------
    {
        float o14[14];
#pragma unroll
        for (int i = 0; i < NJ; i++){
            float qdd = SL(S_TAU(i));
            float qdn = qd[i] + DTF*qdd;
            o14[i]      = q[i] + DTF*qdn;
            o14[NJ + i] = qdn;
        }
        float2* o2 = (float2*)(out + e*14);
#pragma unroll
        for (int i = 0; i < 7; i++){ float2 v; v.x = o14[2*i]; v.y = o14[2*i+1]; o2[i] = v; }
    }
#undef SL
}

extern "C" void kernel_launch(void* const* d_in, const int* in_sizes, int n_in,
                              void* d_out, int out_size, void* d_ws, size_t ws_size,
                              hipStream_t stream) {
    const float* x   = (const float*)d_in[0];
    const float* u   = (const float*)d_in[1];
    const float* ax  = (const float*)d_in[2];
    const float* Rt  = (const float*)d_in[3];
    const float* pt  = (const float*)d_in[4];
    const float* Isp = (const float*)d_in[5];
    float* out = (float*)d_out;
    int B = in_sizes[0] / 14;
    int grid = (B + 63) / 64;
    hipLaunchKernelGGL(panda_step, dim3(grid), dim3(64), 0, stream,
                       x, u, ax, Rt, pt, Isp, out, B);
}